// Round 9
// baseline (278.791 us; speedup 1.0000x reference)
//
#include <hip/hip_runtime.h>
#include <hip/hip_bf16.h>
#include <math.h>
#include <stdint.h>

#define B_ 8
#define T_ 2048
#define E_ 512
#define CCH 256
#define NC_ 8
#define EPS_ 1e-3f
#define QSCALE 0.044194173824159216f   // 512^-0.5

typedef __attribute__((ext_vector_type(8))) short short8;
typedef __attribute__((ext_vector_type(4))) short short4v;
typedef __attribute__((ext_vector_type(4))) float f32x4;
typedef __hip_bfloat16 bf16_t;

__device__ __forceinline__ short f2bs(float x) {
    bf16_t h = __float2bfloat16(x);
    return __builtin_bit_cast(short, h);
}
__device__ __forceinline__ float bs2f(short s) {
    bf16_t h = __builtin_bit_cast(bf16_t, s);
    return __bfloat162float(h);
}

// async global->LDS, 16B per lane; LDS dest is wave-uniform base + lane*16
__device__ __forceinline__ void async16(const void* g, void* l) {
    __builtin_amdgcn_global_load_lds(
        (const __attribute__((address_space(1))) unsigned int*)(unsigned long long)(uintptr_t)g,
        (__attribute__((address_space(3))) unsigned int*)(unsigned int)(uintptr_t)l,
        16, 0, 0);
}

// ---------------------------------------------------------------------------
// GEMM core: C[128x128] += A[128xK] * (B^T[128xK])^T, bf16 in, fp32 acc.
// BK=64, single-buffer 32KB LDS, XOR-swizzled (R7): DMA 8-lane groups cover
// 128B-contiguous row segments; fragment reads 2-way bank alias only (free).
// ---------------------------------------------------------------------------
__device__ __forceinline__ void gemm128(const short* __restrict__ Ag, int lda,
                                        const short* __restrict__ Bg, int ldb, int K,
                                        short* L, f32x4 acc[4][4],
                                        int wm, int wn, int wq, int lane) {
    int m16 = lane & 15, quad = lane >> 4;
    int lrow = lane >> 3;              // 0..7
    int lchunk = (lane & 7) ^ lrow;    // swizzled global 16B-chunk
    short* Bl = L + 8192;
    for (int k0 = 0; k0 < K; k0 += 64) {
        __syncthreads();               // WAR: all reads of prev tile done
        #pragma unroll
        for (int w = 0; w < 4; ++w) {
            int R = wq * 32 + w * 8;
            async16(Ag + (size_t)(R + lrow) * lda + k0 + lchunk * 8, L + R * 64);
            async16(Bg + (size_t)(R + lrow) * ldb + k0 + lchunk * 8, Bl + R * 64);
        }
        __syncthreads();               // drains DMA (compiler vmcnt(0))
        #pragma unroll
        for (int h = 0; h < 2; ++h) {
            int cs = ((h * 4 + quad) ^ (m16 & 7)) * 8;
            short8 a[4], b[4];
            #pragma unroll
            for (int t = 0; t < 4; ++t)
                a[t] = *(const short8*)(L + (wm + t * 16 + m16) * 64 + cs);
            #pragma unroll
            for (int t = 0; t < 4; ++t)
                b[t] = *(const short8*)(Bl + (wn + t * 16 + m16) * 64 + cs);
            #pragma unroll
            for (int t = 0; t < 4; ++t)
                #pragma unroll
                for (int j = 0; j < 4; ++j)
                    acc[t][j] = __builtin_amdgcn_mfma_f32_16x16x32_bf16(a[t], b[j], acc[t][j], 0, 0, 0);
        }
    }
}

#define GEMM_PROLOG \
    int tid = threadIdx.x, lane = tid & 63, wq = tid >> 6; \
    int wm = (wq & 1) * 64, wn = (wq >> 1) * 64; \
    int m16 = lane & 15, quad = lane >> 4; \
    (void)tid; \
    f32x4 acc[4][4]; \
    { f32x4 zz = {0.f, 0.f, 0.f, 0.f}; \
      for (int i = 0; i < 4; ++i) for (int j = 0; j < 4; ++j) acc[i][j] = zz; }

// ---------------------------------------------------------------------------
// prep: [0,512) weights fp32->bf16; [512,2560) transpose x; [2560,2624) WvT.
// WvT[e][ev] = v_w[ev][e] as bf16 (for the Wvo = Wo@Wv pre-GEMM).
// ---------------------------------------------------------------------------
__global__ void prep_kernel(const float* __restrict__ qw, const float* __restrict__ kw,
                            const float* __restrict__ vw, const float* __restrict__ ow,
                            short* __restrict__ wbf,
                            const float* __restrict__ x, short* __restrict__ xbf,
                            short* __restrict__ wvT) {
    __shared__ __align__(16) float S[64][68];
    int bid = blockIdx.x;
    int tid = threadIdx.x;
    if (bid < 512) {
        size_t idx8 = ((size_t)bid * 256 + tid) * 8;
        int sel = (int)(idx8 >> 18);
        size_t off = idx8 & ((1u << 18) - 1);
        const float* src = sel == 0 ? qw : sel == 1 ? kw : sel == 2 ? vw : ow;
        const float4* sp = (const float4*)(src + off);
        float4 a = sp[0], b = sp[1];
        short8 g;
        g[0] = f2bs(a.x); g[1] = f2bs(a.y); g[2] = f2bs(a.z); g[3] = f2bs(a.w);
        g[4] = f2bs(b.x); g[5] = f2bs(b.y); g[6] = f2bs(b.z); g[7] = f2bs(b.w);
        *(short8*)(wbf + idx8) = g;
        return;
    }
    bid -= 512;
    if (bid < 2048) {                     // x (B,E,T) -> xbf (B,T,E)
        int t0 = (bid & 31) * 64, e0 = ((bid >> 5) & 7) * 64, b = bid >> 8;
        const float* src = x + ((size_t)b * E_ + e0) * T_ + t0;
        short* dst = xbf + ((size_t)b * T_ + t0) * E_ + e0;
        #pragma unroll
        for (int p = 0; p < 2; ++p) {
            int el = p * 32 + (tid >> 3), tc = (tid & 7) * 8;
            const float4* sp = (const float4*)(src + (size_t)el * T_ + tc);
            *(float4*)&S[el][tc] = sp[0];
            *(float4*)&S[el][tc + 4] = sp[1];
        }
        __syncthreads();
        #pragma unroll
        for (int p = 0; p < 2; ++p) {
            int tl = p * 32 + (tid >> 3), ec = (tid & 7) * 8;
            short8 g;
            #pragma unroll
            for (int j = 0; j < 8; ++j) g[j] = f2bs(S[ec + j][tl]);
            *(short8*)(dst + (size_t)tl * E_ + ec) = g;
        }
        return;
    }
    bid -= 2048;                          // v_w [ev][e] -> WvT [e][ev]
    int ev0 = (bid & 7) * 64, e0 = (bid >> 3) * 64;
    const float* src = vw + (size_t)ev0 * E_ + e0;
    short* dst = wvT + (size_t)e0 * E_ + ev0;
    #pragma unroll
    for (int p = 0; p < 2; ++p) {
        int evl = p * 32 + (tid >> 3), ec = (tid & 7) * 8;
        const float4* sp = (const float4*)(src + (size_t)evl * E_ + ec);
        *(float4*)&S[evl][ec] = sp[0];
        *(float4*)&S[evl][ec + 4] = sp[1];
    }
    __syncthreads();
    #pragma unroll
    for (int p = 0; p < 2; ++p) {
        int er = p * 32 + (tid >> 3), evc = (tid & 7) * 8;
        short8 g;
        #pragma unroll
        for (int j = 0; j < 8; ++j) g[j] = f2bs(S[evc + j][er]);
        *(short8*)(dst + (size_t)er * E_ + evc) = g;
    }
}

// ---------------------------------------------------------------------------
// blocks 0..15: Wvo[i,e] = sum_ev Wo[i,ev]*Wv[ev,e]  (A=wbf_o, B^T=wvT)
// block 16: bvo[i] = sum_e Wo[i,e]*v_b[e]  (fp32)
// ---------------------------------------------------------------------------
__global__ __launch_bounds__(256) void wvo_kernel(
    const short* __restrict__ wbf_o, const short* __restrict__ wvT,
    const float* __restrict__ ow, const float* __restrict__ vb,
    short* __restrict__ wvo, float* __restrict__ bvo) {
    __shared__ __align__(16) short L[16384];
    int bid = blockIdx.x;
    if (bid == 16) {
        int tid = threadIdx.x;
        #pragma unroll
        for (int rep = 0; rep < 2; ++rep) {
            int i = rep * 256 + tid;
            float s = 0.f;
            for (int e = 0; e < E_; ++e) s += ow[(size_t)i * E_ + e] * vb[e];
            bvo[i] = s;
        }
        return;
    }
    GEMM_PROLOG
    int e0 = (bid & 3) * 128, i0 = (bid >> 2) * 128;
    gemm128(wbf_o + (size_t)i0 * E_, E_, wvT + (size_t)e0 * E_, E_, E_,
            L, acc, wm, wn, wq, lane);
    #pragma unroll
    for (int mt = 0; mt < 4; ++mt)
        #pragma unroll
        for (int r = 0; r < 4; ++r) {
            int i = i0 + wm + mt * 16 + quad * 4 + r;
            #pragma unroll
            for (int nt = 0; nt < 4; ++nt) {
                int e = e0 + wn + nt * 16 + m16;
                wvo[(size_t)i * E_ + e] = f2bs(acc[mt][nt][r]);
            }
        }
}

// ---------------------------------------------------------------------------
// fused q/k/vw projections. sel0: qraw (T,E). sel1: k=exp -> kbf (T,E) + kT (E,T).
// sel2: vw = (x@Wvo^T + bvo)*toep -> vwT (E,T) only (rotated basis).
// ---------------------------------------------------------------------------
__global__ __launch_bounds__(256) void proj_qkv_kernel(
    const short* __restrict__ xbf, const short* __restrict__ wbf,
    const short* __restrict__ wvo,
    const float* __restrict__ qb, const float* __restrict__ kb, const float* __restrict__ bvo,
    const float* __restrict__ toep,
    short* __restrict__ qraw, short* __restrict__ kbf,
    short* __restrict__ kT, short* __restrict__ vwT) {
    __shared__ __align__(16) short L[16384];
    GEMM_PROLOG
    int t0 = blockIdx.x * 128, i0 = blockIdx.y * 128;
    int b = blockIdx.z / 3, sel = blockIdx.z % 3;
    const short* Ag = xbf + ((size_t)b * T_ + t0) * E_;
    const short* Bg = (sel == 2) ? (wvo + (size_t)i0 * E_)
                                 : (wbf + (size_t)sel * E_ * E_ + (size_t)i0 * E_);
    gemm128(Ag, E_, Bg, E_, E_, L, acc, wm, wn, wq, lane);
    const float* bias = (sel == 0) ? qb : (sel == 1) ? kb : bvo;

    short4v ov[4][4];
    #pragma unroll
    for (int mt = 0; mt < 4; ++mt)
        #pragma unroll
        for (int r = 0; r < 4; ++r) {
            int t = t0 + wm + mt * 16 + quad * 4 + r;
            float tw = toep[t];
            #pragma unroll
            for (int nt = 0; nt < 4; ++nt) {
                int col = i0 + wn + nt * 16 + m16;
                float vv = acc[mt][nt][r] + bias[col];
                if (sel == 1) vv = expf(vv);
                if (sel == 2) vv = vv * tw;
                ov[mt][nt][r] = f2bs(vv);
            }
        }

    if (sel <= 1) {
        short* dst = (sel == 0) ? qraw : kbf;
        #pragma unroll
        for (int mt = 0; mt < 4; ++mt)
            #pragma unroll
            for (int r = 0; r < 4; ++r) {
                int t = t0 + wm + mt * 16 + quad * 4 + r;
                #pragma unroll
                for (int nt = 0; nt < 4; ++nt) {
                    int col = i0 + wn + nt * 16 + m16;
                    dst[((size_t)b * T_ + t) * E_ + col] = ov[mt][nt][r];
                }
            }
    }

    if (sel >= 1) {
        short* dstT = (sel == 1) ? kT : vwT;
        #pragma unroll
        for (int h = 0; h < 2; ++h) {
            __syncthreads();
            if (wm == 64 * h) {
                #pragma unroll
                for (int mt = 0; mt < 4; ++mt)
                    #pragma unroll
                    for (int nt = 0; nt < 4; ++nt) {
                        int col = wn + nt * 16 + m16;
                        int tl = mt * 16 + quad * 4;
                        *(short4v*)&L[col * 68 + tl] = ov[mt][nt];
                    }
            }
            __syncthreads();
            #pragma unroll
            for (int rnd = 0; rnd < 4; ++rnd) {
                int col = rnd * 32 + (tid >> 3);
                int tt = (tid & 7) * 8;
                short8 g = *(const short8*)&L[col * 68 + tt];
                *(short8*)(dstT + ((size_t)b * E_ + i0 + col) * T_ + t0 + 64 * h + tt) = g;
            }
        }
    }
}

// ---------------------------------------------------------------------------
// blocks [0,16384): softmax over q rows; blocks [16384,16512): per-chunk ksum
// ---------------------------------------------------------------------------
__global__ void softmax_ksum_kernel(const short* __restrict__ qraw, short* __restrict__ qbf,
                                    const short* __restrict__ k, float* __restrict__ ks) {
    int bid = blockIdx.x, tid = threadIdx.x;
    if (bid >= B_ * T_) {
        int r = bid - B_ * T_;
        int bc = r >> 1, b = bc >> 3, c = bc & 7;
        int e = (r & 1) * 256 + tid;
        const short* kp = k + ((size_t)b * T_ + (size_t)c * CCH) * E_ + e;
        float s = 0.f;
        for (int t = 0; t < CCH; ++t) s += bs2f(kp[(size_t)t * E_]);
        ks[(size_t)bc * E_ + e] = s;
        return;
    }
    __shared__ float red[256];
    const short* p = qraw + (size_t)bid * E_;
    float v0 = bs2f(p[tid]), v1 = bs2f(p[tid + 256]);
    red[tid] = fmaxf(v0, v1);
    __syncthreads();
    for (int s = 128; s > 0; s >>= 1) { if (tid < s) red[tid] = fmaxf(red[tid], red[tid + s]); __syncthreads(); }
    float m = red[0];
    __syncthreads();
    float e0 = expf(v0 - m), e1 = expf(v1 - m);
    red[tid] = e0 + e1;
    __syncthreads();
    for (int s = 128; s > 0; s >>= 1) { if (tid < s) red[tid] += red[tid + s]; __syncthreads(); }
    float inv = QSCALE / red[0];
    qbf[(size_t)bid * E_ + tid] = f2bs(e0 * inv);
    qbf[(size_t)bid * E_ + tid + 256] = f2bs(e1 * inv);
}

// ---------------------------------------------------------------------------
// blocks [0,1024): chunk KV (rotated: KV[i, ek] = sum_t Vw[t,i] k[t,ek]);
// blocks [1024,1280): intra-chunk P matrix
// ---------------------------------------------------------------------------
__global__ __launch_bounds__(256) void kvp_kernel(
    const short* __restrict__ vwT, const short* __restrict__ kT, short* __restrict__ KV,
    const short* __restrict__ qbf, const short* __restrict__ kbf, short* __restrict__ P) {
    __shared__ __align__(16) short L[16384];
    int bid = blockIdx.x;
    if (bid < 1024) {
        GEMM_PROLOG
        int ev0 = (bid & 3) * 128, ek0 = ((bid >> 2) & 3) * 128;
        int bc = bid >> 4, b = bc >> 3, c = bc & 7;
        const short* Ag = vwT + ((size_t)b * E_ + ev0) * T_ + c * CCH;
        const short* Bg = kT + ((size_t)b * E_ + ek0) * T_ + c * CCH;
        gemm128(Ag, T_, Bg, T_, CCH, L, acc, wm, wn, wq, lane);
        #pragma unroll
        for (int mt = 0; mt < 4; ++mt)
            #pragma unroll
            for (int r = 0; r < 4; ++r) {
                int ev = ev0 + wm + mt * 16 + quad * 4 + r;
                #pragma unroll
                for (int nt = 0; nt < 4; ++nt) {
                    int ek = ek0 + wn + nt * 16 + m16;
                    KV[((size_t)bc * E_ + ev) * E_ + ek] = f2bs(acc[mt][nt][r]);
                }
            }
        return;
    }
    bid -= 1024;
    int tj0 = (bid & 1) * 128, ti0 = ((bid >> 1) & 1) * 128;
    int bc = bid >> 2, b = bc >> 3, c = bc & 7;
    short* Pp = P + (size_t)bc * CCH * CCH;
    if (tj0 > ti0) {
        short8 z8 = {0, 0, 0, 0, 0, 0, 0, 0};
        for (int i = threadIdx.x; i < 128 * 128 / 8; i += 256) {
            int row = i >> 4, colc = (i * 8) & 127;
            *(short8*)(Pp + (size_t)(ti0 + row) * CCH + tj0 + colc) = z8;
        }
        return;
    }
    GEMM_PROLOG
    const short* Ag = qbf + ((size_t)b * T_ + c * CCH + ti0) * E_;
    const short* Bg = kbf + ((size_t)b * T_ + c * CCH + tj0) * E_;
    gemm128(Ag, E_, Bg, E_, E_, L, acc, wm, wn, wq, lane);
    #pragma unroll
    for (int mt = 0; mt < 4; ++mt)
        #pragma unroll
        for (int r = 0; r < 4; ++r) {
            int row = ti0 + wm + mt * 16 + quad * 4 + r;
            #pragma unroll
            for (int nt = 0; nt < 4; ++nt) {
                int col = tj0 + wn + nt * 16 + m16;
                float vv = (col <= row) ? acc[mt][nt][r] : 0.f;
                Pp[(size_t)row * CCH + col] = f2bs(vv);
            }
        }
}

// ---------------------------------------------------------------------------
// blocks [0,1024): exclusive chunk-scan of KV (bf16, 8 elem/thread);
// blocks [1024,1040): fp32 exclusive chunk-scan of ksum
// ---------------------------------------------------------------------------
__global__ void scan2_kernel(short* __restrict__ KV, float* __restrict__ ks) {
    int bid = blockIdx.x, tid = threadIdx.x;
    if (bid < 1024) {
        int gid = bid * 256 + tid;
        int b = gid >> 15;
        size_t idx = (size_t)(gid & 32767) * 8;
        short* p = KV + (size_t)b * NC_ * E_ * E_ + idx;
        float run[8] = {0.f, 0.f, 0.f, 0.f, 0.f, 0.f, 0.f, 0.f};
        #pragma unroll
        for (int c = 0; c < NC_; ++c) {
            short8 t8 = *(short8*)p;
            short8 o8;
            #pragma unroll
            for (int j = 0; j < 8; ++j) {
                float tv = bs2f(t8[j]);
                o8[j] = f2bs(run[j]);
                run[j] += tv;
            }
            *(short8*)p = o8;
            p += (size_t)E_ * E_;
        }
        return;
    }
    int gid = (bid - 1024) * 256 + tid;
    int b = gid >> 9, idx = gid & (E_ - 1);
    float run = 0.f;
    float* p = ks + (size_t)b * NC_ * E_ + idx;
    for (int c = 0; c < NC_; ++c) { float t = *p; *p = run; run += t; p += E_; }
}

// ---------------------------------------------------------------------------
__global__ void denom_kernel(const short* __restrict__ qbf, const float* __restrict__ z,
                             const short* __restrict__ P, float* __restrict__ invd) {
    __shared__ float red[256];
    int row = blockIdx.x, tid = threadIdx.x;
    int b = row >> 11, t = row & (T_ - 1);
    int c = t >> 8, tl = t & 255;
    const short* qr = qbf + (size_t)row * E_;
    const float* zr = z + ((size_t)(b * NC_ + c)) * E_;
    const short* Pr = P + (((size_t)(b * NC_ + c)) * CCH + tl) * CCH;
    float s = bs2f(qr[tid]) * zr[tid]
            + bs2f(qr[tid + 256]) * zr[tid + 256]
            + bs2f(Pr[tid]);
    red[tid] = s;
    __syncthreads();
    for (int st = 128; st > 0; st >>= 1) { if (tid < st) red[tid] += red[tid + st]; __syncthreads(); }
    if (tid == 0) invd[row] = 1.f / fmaxf(red[0], EPS_);
}

// ---------------------------------------------------------------------------
// attnout in rotated basis: out[t,i] = (q@S' + P@Vw)[t,i]*invd[t] + o_b[i]  (fp32)
// ---------------------------------------------------------------------------
__global__ __launch_bounds__(256) void attnout_kernel(
    const short* __restrict__ qbf, const short* __restrict__ KV,
    const short* __restrict__ P, const short* __restrict__ vwT,
    const float* __restrict__ invd, const float* __restrict__ ob,
    float* __restrict__ out) {
    __shared__ __align__(16) short L[16384];
    GEMM_PROLOG
    int t0 = blockIdx.x * 128, i0 = blockIdx.y * 128, b = blockIdx.z;
    int c = t0 >> 8, tl0 = t0 & 255, bc = b * NC_ + c;
    gemm128(qbf + ((size_t)b * T_ + t0) * E_, E_,
            KV + ((size_t)bc * E_ + i0) * E_, E_, E_, L, acc, wm, wn, wq, lane);
    gemm128(P + ((size_t)bc * CCH + tl0) * CCH, CCH,
            vwT + ((size_t)b * E_ + i0) * T_ + c * CCH, T_, CCH, L, acc, wm, wn, wq, lane);
    #pragma unroll
    for (int mt = 0; mt < 4; ++mt)
        #pragma unroll
        for (int r = 0; r < 4; ++r) {
            int t = t0 + wm + mt * 16 + quad * 4 + r;
            float sc = invd[(size_t)b * T_ + t];
            #pragma unroll
            for (int nt = 0; nt < 4; ++nt) {
                int col = i0 + wn + nt * 16 + m16;
                out[((size_t)b * T_ + t) * E_ + col] = acc[mt][nt][r] * sc + ob[col];
            }
        }
}

// ---------------------------------------------------------------------------
extern "C" void kernel_launch(void* const* d_in, const int* in_sizes, int n_in,
                              void* d_out, int out_size, void* d_ws, size_t ws_size,
                              hipStream_t stream) {
    const float* x    = (const float*)d_in[0];
    const float* toep = (const float*)d_in[1];
    const float* q_w  = (const float*)d_in[2];
    const float* q_b  = (const float*)d_in[3];
    const float* k_w  = (const float*)d_in[4];
    const float* k_b  = (const float*)d_in[5];
    const float* v_w  = (const float*)d_in[6];
    const float* v_b  = (const float*)d_in[7];
    const float* o_w  = (const float*)d_in[8];
    const float* o_b  = (const float*)d_in[9];

    const size_t NTE = (size_t)B_ * T_ * E_;          // 8388608
    char* base = (char*)d_ws;
    short* xbf  = (short*)base;  base += NTE * 2;
    short* wbf  = (short*)base;  base += (size_t)4 * E_ * E_ * 2;
    short* wvT  = (short*)base;  base += (size_t)E_ * E_ * 2;
    short* wvo  = (short*)base;  base += (size_t)E_ * E_ * 2;
    float* bvo  = (float*)base;  base += (size_t)E_ * 4;
    short* qraw = (short*)base;  base += NTE * 2;
    short* qbf  = (short*)base;  base += NTE * 2;
    short* kbf  = (short*)base;  base += NTE * 2;
    short* kT   = (short*)base;  base += NTE * 2;
    short* vwT  = (short*)base;  base += NTE * 2;
    short* KV   = (short*)base;  base += (size_t)B_ * NC_ * E_ * E_ * 2;
    short* P    = (short*)base;  base += (size_t)B_ * NC_ * CCH * CCH * 2;
    float* ksum = (float*)base;  base += (size_t)B_ * NC_ * E_ * 4;
    float* invd = (float*)base;  base += (size_t)B_ * T_ * 4;
    float* out  = (float*)d_out;

    dim3 blk(256);
    prep_kernel<<<dim3(2624), blk, 0, stream>>>(q_w, k_w, v_w, o_w, wbf, x, xbf, wvT);
    wvo_kernel<<<dim3(17), blk, 0, stream>>>(
        wbf + (size_t)3 * E_ * E_, wvT, o_w, v_b, wvo, bvo);
    proj_qkv_kernel<<<dim3(16, 4, 24), blk, 0, stream>>>(
        xbf, wbf, wvo, q_b, k_b, bvo, toep, qraw, kbf, kT, vwT);
    softmax_ksum_kernel<<<dim3(B_ * T_ + 128), blk, 0, stream>>>(
        qraw, qbf, kbf, ksum);
    kvp_kernel<<<dim3(1280), blk, 0, stream>>>(
        vwT, kT, KV, qbf, kbf, P);
    scan2_kernel<<<dim3(1040), blk, 0, stream>>>(KV, ksum);
    denom_kernel<<<dim3(B_ * T_), blk, 0, stream>>>(
        qbf, ksum, P, invd);
    attnout_kernel<<<dim3(16, 4, 8), blk, 0, stream>>>(
        qbf, KV, P, vwT, invd, o_b, out);
}